// Round 6
// baseline (471.315 us; speedup 1.0000x reference)
//
#include <hip/hip_runtime.h>
#include <stdint.h>
#include <stddef.h>

typedef __attribute__((ext_vector_type(8))) short bf16x8;
typedef __attribute__((ext_vector_type(4))) float f32x4;

#define NROWS 400000
#define KC 128
#define DIMS 64
#define NTILES (NROWS / 16)

__device__ __forceinline__ short f2bf(float f) {
    union { float f; uint32_t u; } v; v.f = f;
    uint32_t u = v.u;
    uint32_t r = (u + 0x7FFFu + ((u >> 16) & 1u)) >> 16;  // RNE, finite inputs
    return (short)r;
}

__device__ __forceinline__ float frcp(float x) { return __builtin_amdgcn_rcpf(x); }

// Stage center bf16 fragments into LDS (wave 0), cnorm in regs (norm of center cb*16+m).
__device__ __forceinline__ void stage_centers(
        const float* __restrict__ centers, bf16x8 (*blds)[2][64],
        float* cnorm, int wid, int lane, int m, int g)
{
    #pragma unroll
    for (int cb = 0; cb < 8; ++cb) {
        float cacc = 0.f;
        bf16x8 bfr[2];
        #pragma unroll
        for (int h = 0; h < 2; ++h) {
            const float* src = centers + (size_t)(cb * 16 + m) * DIMS + h * 32 + g * 8;
            f32x4 c0 = *(const f32x4*)src;
            f32x4 c1 = *(const f32x4*)(src + 4);
            bf16x8 b;
            #pragma unroll
            for (int j = 0; j < 4; ++j) {
                float f0 = c0[j], f1 = c1[j];
                cacc += f0 * f0 + f1 * f1;
                b[j]     = f2bf(f0);
                b[j + 4] = f2bf(f1);
            }
            bfr[h] = b;
        }
        cacc += __shfl_xor(cacc, 16);
        cacc += __shfl_xor(cacc, 32);
        cnorm[cb] = cacc;
        if (wid == 0) { blds[cb][0][lane] = bfr[0]; blds[cb][1][lane] = bfr[1]; }
    }
    __syncthreads();
}

// K1: column sums of q. Reads embeds only; partials written TRANSPOSED [k][block].
// VGPR ~84 natural -> 6 blocks/CU resident; grid must be 256*6.
__global__ __launch_bounds__(256, 6) void k1_colsum(
        const float* __restrict__ embeds, const float* __restrict__ centers,
        float* __restrict__ colsum_part, int nblocks)
{
    __shared__ bf16x8 blds[8][2][64];
    __shared__ float cl[4 * 128];
    const int tid = threadIdx.x, wid = tid >> 6, lane = tid & 63;
    const int m = lane & 15, g = lane >> 4;

    float cnorm[8];
    stage_centers(centers, blds, cnorm, wid, lane, m, g);

    float csum[8];
    #pragma unroll
    for (int cb = 0; cb < 8; ++cb) csum[cb] = 0.f;

    const int gwid = blockIdx.x * 4 + wid;
    const int nw = nblocks * 4;

    int t = gwid;
    f32x4 n0, n1, n2, n3;
    if (t < NTILES) {
        const float* src = embeds + (size_t)(t * 16 + m) * DIMS + g * 8;
        n0 = *(const f32x4*)src;       n1 = *(const f32x4*)(src + 4);
        n2 = *(const f32x4*)(src + 32); n3 = *(const f32x4*)(src + 36);
    }
    for (; t < NTILES; t += nw) {
        f32x4 c0 = n0, c1 = n1, c2 = n2, c3 = n3;
        int tn = t + nw;
        if (tn < NTILES) {
            const float* src = embeds + (size_t)(tn * 16 + m) * DIMS + g * 8;
            n0 = *(const f32x4*)src;       n1 = *(const f32x4*)(src + 4);
            n2 = *(const f32x4*)(src + 32); n3 = *(const f32x4*)(src + 36);
        }
        bf16x8 a0, a1;
        float en = 0.f;
        #pragma unroll
        for (int j = 0; j < 4; ++j) {
            float f0 = c0[j], f1 = c1[j], f2 = c2[j], f3 = c3[j];
            en += f0 * f0 + f1 * f1 + f2 * f2 + f3 * f3;
            a0[j] = f2bf(f0); a0[j + 4] = f2bf(f1);
            a1[j] = f2bf(f2); a1[j + 4] = f2bf(f3);
        }
        en += __shfl_xor(en, 16);
        en += __shfl_xor(en, 32);
        float er[4];
        #pragma unroll
        for (int r = 0; r < 4; ++r) er[r] = __shfl(en, g * 4 + r);

        f32x4 acc[8];
        #pragma unroll
        for (int cb = 0; cb < 8; ++cb) {
            bf16x8 b0 = blds[cb][0][lane];
            bf16x8 b1 = blds[cb][1][lane];
            f32x4 a = {0.f, 0.f, 0.f, 0.f};
            a = __builtin_amdgcn_mfma_f32_16x16x32_bf16(a0, b0, a, 0, 0, 0);
            a = __builtin_amdgcn_mfma_f32_16x16x32_bf16(a1, b1, a, 0, 0, 0);
            acc[cb] = a;
        }

        float rs[4] = {0.f, 0.f, 0.f, 0.f};
        #pragma unroll
        for (int cb = 0; cb < 8; ++cb) {
            #pragma unroll
            for (int r = 0; r < 4; ++r) {
                float sq = fmaxf(er[r] + cnorm[cb] - 2.0f * acc[cb][r], 0.f);
                float dist = frcp(1.0f + sq);
                acc[cb][r] = dist;
                rs[r] += dist;
            }
        }
        #pragma unroll
        for (int r = 0; r < 4; ++r) {
            rs[r] += __shfl_xor(rs[r], 1);
            rs[r] += __shfl_xor(rs[r], 2);
            rs[r] += __shfl_xor(rs[r], 4);
            rs[r] += __shfl_xor(rs[r], 8);
            rs[r] = frcp(rs[r]);
        }
        #pragma unroll
        for (int cb = 0; cb < 8; ++cb) {
            #pragma unroll
            for (int r = 0; r < 4; ++r) csum[cb] += acc[cb][r] * rs[r];
        }
    }

    #pragma unroll
    for (int cb = 0; cb < 8; ++cb) {
        csum[cb] += __shfl_xor(csum[cb], 16);
        csum[cb] += __shfl_xor(csum[cb], 32);
    }
    if (lane < 16) {
        #pragma unroll
        for (int cb = 0; cb < 8; ++cb) cl[wid * 128 + cb * 16 + lane] = csum[cb];
    }
    __syncthreads();
    if (tid < 128) {
        float s = cl[tid] + cl[128 + tid] + cl[256 + tid] + cl[384 + tid];
        colsum_part[(size_t)tid * nblocks + blockIdx.x] = s;   // transposed
    }
}

// K1b: 128 blocks, block k reduces contiguous row k -> invS[k], log2S[k]
__global__ __launch_bounds__(256) void k1b_reduce(
        const float* __restrict__ part, float* __restrict__ invS,
        float* __restrict__ lS, int nb)
{
    __shared__ float lds[4];
    const int k = blockIdx.x;
    const int tid = threadIdx.x, wid = tid >> 6, lane = tid & 63;
    float s = 0.f;
    for (int b = tid; b < nb; b += 256) s += part[(size_t)k * nb + b];
    s += __shfl_xor(s, 1);  s += __shfl_xor(s, 2);  s += __shfl_xor(s, 4);
    s += __shfl_xor(s, 8);  s += __shfl_xor(s, 16); s += __shfl_xor(s, 32);
    if (lane == 0) lds[wid] = s;
    __syncthreads();
    if (tid == 0) {
        float tot = lds[0] + lds[1] + lds[2] + lds[3];
        invS[k] = 1.0f / tot;
        lS[k] = __log2f(tot);
    }
}

// K2: recompute dist, write q, fused loss (log2 domain).
// VGPR 84 measured -> 6 blocks/CU; grid 1536 matches residency.
__global__ __launch_bounds__(256, 6) void k2_q_loss(
        const float* __restrict__ embeds, const float* __restrict__ centers,
        const float* __restrict__ invS, const float* __restrict__ lS,
        float* __restrict__ q, float* __restrict__ losspart, int nblocks)
{
    __shared__ bf16x8 blds[8][2][64];
    __shared__ float lds4[4];
    const int tid = threadIdx.x, wid = tid >> 6, lane = tid & 63;
    const int m = lane & 15, g = lane >> 4;

    float cnorm[8];
    stage_centers(centers, blds, cnorm, wid, lane, m, g);

    float invSr[8], lSr[8];
    #pragma unroll
    for (int cb = 0; cb < 8; ++cb) {
        invSr[cb] = invS[cb * 16 + m];
        lSr[cb]   = lS[cb * 16 + m];
    }

    float loss = 0.f;
    const int gwid = blockIdx.x * 4 + wid;
    const int nw = nblocks * 4;

    int t = gwid;
    f32x4 n0, n1, n2, n3;
    if (t < NTILES) {
        const float* src = embeds + (size_t)(t * 16 + m) * DIMS + g * 8;
        n0 = *(const f32x4*)src;       n1 = *(const f32x4*)(src + 4);
        n2 = *(const f32x4*)(src + 32); n3 = *(const f32x4*)(src + 36);
    }
    for (; t < NTILES; t += nw) {
        f32x4 c0 = n0, c1 = n1, c2 = n2, c3 = n3;
        int tn = t + nw;
        if (tn < NTILES) {
            const float* src = embeds + (size_t)(tn * 16 + m) * DIMS + g * 8;
            n0 = *(const f32x4*)src;       n1 = *(const f32x4*)(src + 4);
            n2 = *(const f32x4*)(src + 32); n3 = *(const f32x4*)(src + 36);
        }
        bf16x8 a0, a1;
        float en = 0.f;
        #pragma unroll
        for (int j = 0; j < 4; ++j) {
            float f0 = c0[j], f1 = c1[j], f2 = c2[j], f3 = c3[j];
            en += f0 * f0 + f1 * f1 + f2 * f2 + f3 * f3;
            a0[j] = f2bf(f0); a0[j + 4] = f2bf(f1);
            a1[j] = f2bf(f2); a1[j + 4] = f2bf(f3);
        }
        en += __shfl_xor(en, 16);
        en += __shfl_xor(en, 32);
        float er[4];
        #pragma unroll
        for (int r = 0; r < 4; ++r) er[r] = __shfl(en, g * 4 + r);

        f32x4 acc[8];
        #pragma unroll
        for (int cb = 0; cb < 8; ++cb) {
            bf16x8 b0 = blds[cb][0][lane];
            bf16x8 b1 = blds[cb][1][lane];
            f32x4 a = {0.f, 0.f, 0.f, 0.f};
            a = __builtin_amdgcn_mfma_f32_16x16x32_bf16(a0, b0, a, 0, 0, 0);
            a = __builtin_amdgcn_mfma_f32_16x16x32_bf16(a1, b1, a, 0, 0, 0);
            acc[cb] = a;
        }

        float rs[4] = {0.f, 0.f, 0.f, 0.f};
        #pragma unroll
        for (int cb = 0; cb < 8; ++cb) {
            #pragma unroll
            for (int r = 0; r < 4; ++r) {
                float sq = fmaxf(er[r] + cnorm[cb] - 2.0f * acc[cb][r], 0.f);
                float dist = frcp(1.0f + sq);
                acc[cb][r] = dist;
                rs[r] += dist;
            }
        }
        #pragma unroll
        for (int r = 0; r < 4; ++r) {
            rs[r] += __shfl_xor(rs[r], 1);
            rs[r] += __shfl_xor(rs[r], 2);
            rs[r] += __shfl_xor(rs[r], 4);
            rs[r] += __shfl_xor(rs[r], 8);
            rs[r] = frcp(rs[r]);
        }

        float W[4] = {0.f, 0.f, 0.f, 0.f};
        #pragma unroll
        for (int cb = 0; cb < 8; ++cb) {
            #pragma unroll
            for (int r = 0; r < 4; ++r) {
                float qv = acc[cb][r] * rs[r];
                acc[cb][r] = qv;
                q[(size_t)(t * 16 + g * 4 + r) * KC + cb * 16 + m] = qv;
                W[r] += qv * qv * invSr[cb];
            }
        }
        float iw[4], lw[4];
        #pragma unroll
        for (int r = 0; r < 4; ++r) {
            W[r] += __shfl_xor(W[r], 1);
            W[r] += __shfl_xor(W[r], 2);
            W[r] += __shfl_xor(W[r], 4);
            W[r] += __shfl_xor(W[r], 8);
            iw[r] = frcp(W[r]);
            lw[r] = __log2f(W[r]);
        }
        #pragma unroll
        for (int cb = 0; cb < 8; ++cb) {
            #pragma unroll
            for (int r = 0; r < 4; ++r) {
                float qv = acc[cb][r];
                float w = qv * qv * invSr[cb];
                loss += w * iw[r] * (__log2f(qv) - lSr[cb] - lw[r]);
            }
        }
    }

    loss += __shfl_xor(loss, 1);  loss += __shfl_xor(loss, 2);
    loss += __shfl_xor(loss, 4);  loss += __shfl_xor(loss, 8);
    loss += __shfl_xor(loss, 16); loss += __shfl_xor(loss, 32);
    if (lane == 0) lds4[wid] = loss;
    __syncthreads();
    if (tid == 0) losspart[blockIdx.x] = lds4[0] + lds4[1] + lds4[2] + lds4[3];
}

// K2b: final loss reduce; convert log2 -> ln
__global__ __launch_bounds__(1024) void k2b_final(
        const float* __restrict__ losspart, int nb, float* __restrict__ out)
{
    __shared__ float lds[16];
    const int tid = threadIdx.x;
    float s = 0.f;
    for (int b = tid; b < nb; b += 1024) s += losspart[b];
    s += __shfl_xor(s, 1);  s += __shfl_xor(s, 2);  s += __shfl_xor(s, 4);
    s += __shfl_xor(s, 8);  s += __shfl_xor(s, 16); s += __shfl_xor(s, 32);
    if ((tid & 63) == 0) lds[tid >> 6] = s;
    __syncthreads();
    if (tid == 0) {
        float tot = 0.f;
        #pragma unroll
        for (int i = 0; i < 16; ++i) tot += lds[i];
        out[0] = (float)((double)tot * 0.6931471805599453 /
                         (double)((size_t)NROWS * KC));
    }
}

extern "C" void kernel_launch(void* const* d_in, const int* in_sizes, int n_in,
                              void* d_out, int out_size, void* d_ws, size_t ws_size,
                              hipStream_t stream)
{
    const float* embeds  = (const float*)d_in[0];
    const float* centers = (const float*)d_in[1];
    float* out  = (float*)d_out;
    float* qbuf = out + 1;
    float* ws   = (float*)d_ws;

    int GB1 = 1536, GB2 = 1536;     // 6 blocks/CU x 256 CUs
    size_t need = ((size_t)GB1 * 128 + 256 + (size_t)GB2) * sizeof(float);
    if (need > ws_size) { GB1 = 512; GB2 = 512; }

    float* colsum_part = ws;                          // 128 * GB1 (transposed)
    float* invS  = ws + (size_t)GB1 * 128;            // 128
    float* lS    = invS + 128;                        // 128
    float* lpart = lS + 128;                          // GB2

    hipLaunchKernelGGL(k1_colsum, dim3(GB1), dim3(256), 0, stream,
                       embeds, centers, colsum_part, GB1);
    hipLaunchKernelGGL(k1b_reduce, dim3(128), dim3(256), 0, stream,
                       colsum_part, invS, lS, GB1);
    hipLaunchKernelGGL(k2_q_loss, dim3(GB2), dim3(256), 0, stream,
                       embeds, centers, invS, lS, qbuf, lpart, GB2);
    hipLaunchKernelGGL(k2b_final, dim3(1), dim3(1024), 0, stream,
                       lpart, GB2, out);
}

// Round 7
// 121.215 us; speedup vs baseline: 3.8883x; 3.8883x over previous
//
#include <hip/hip_runtime.h>
#include <stdint.h>
#include <stddef.h>

typedef __attribute__((ext_vector_type(8))) short bf16x8;
typedef __attribute__((ext_vector_type(4))) float f32x4;

#define NROWS 400000
#define KC 128
#define DIMS 64
#define NTILES (NROWS / 16)

__device__ __forceinline__ short f2bf(float f) {
    union { float f; uint32_t u; } v; v.f = f;
    uint32_t u = v.u;
    uint32_t r = (u + 0x7FFFu + ((u >> 16) & 1u)) >> 16;  // RNE, finite inputs
    return (short)r;
}

__device__ __forceinline__ float frcp(float x) { return __builtin_amdgcn_rcpf(x); }

// Stage center bf16 fragments into LDS (wave 0), cnorm in regs (norm of center cb*16+m).
__device__ __forceinline__ void stage_centers(
        const float* __restrict__ centers, bf16x8 (*blds)[2][64],
        float* cnorm, int wid, int lane, int m, int g)
{
    #pragma unroll
    for (int cb = 0; cb < 8; ++cb) {
        float cacc = 0.f;
        bf16x8 bfr[2];
        #pragma unroll
        for (int h = 0; h < 2; ++h) {
            const float* src = centers + (size_t)(cb * 16 + m) * DIMS + h * 32 + g * 8;
            f32x4 c0 = *(const f32x4*)src;
            f32x4 c1 = *(const f32x4*)(src + 4);
            bf16x8 b;
            #pragma unroll
            for (int j = 0; j < 4; ++j) {
                float f0 = c0[j], f1 = c1[j];
                cacc += f0 * f0 + f1 * f1;
                b[j]     = f2bf(f0);
                b[j + 4] = f2bf(f1);
            }
            bfr[h] = b;
        }
        cacc += __shfl_xor(cacc, 16);
        cacc += __shfl_xor(cacc, 32);
        cnorm[cb] = cacc;
        if (wid == 0) { blds[cb][0][lane] = bfr[0]; blds[cb][1][lane] = bfr[1]; }
    }
    __syncthreads();
}

// K1: column sums of q. Reads embeds only; partials written TRANSPOSED [k][block].
// NO min-waves bound: compiler keeps register freedom (R6 lesson).
__global__ __launch_bounds__(256) void k1_colsum(
        const float* __restrict__ embeds, const float* __restrict__ centers,
        float* __restrict__ colsum_part, int nblocks)
{
    __shared__ bf16x8 blds[8][2][64];
    __shared__ float cl[4 * 128];
    const int tid = threadIdx.x, wid = tid >> 6, lane = tid & 63;
    const int m = lane & 15, g = lane >> 4;

    float cnorm[8];
    stage_centers(centers, blds, cnorm, wid, lane, m, g);

    float csum[8];
    #pragma unroll
    for (int cb = 0; cb < 8; ++cb) csum[cb] = 0.f;

    const int gwid = blockIdx.x * 4 + wid;
    const int nw = nblocks * 4;

    int t = gwid;
    f32x4 n0, n1, n2, n3;
    if (t < NTILES) {
        const float* src = embeds + (size_t)(t * 16 + m) * DIMS + g * 8;
        n0 = *(const f32x4*)src;       n1 = *(const f32x4*)(src + 4);
        n2 = *(const f32x4*)(src + 32); n3 = *(const f32x4*)(src + 36);
    }
    for (; t < NTILES; t += nw) {
        f32x4 c0 = n0, c1 = n1, c2 = n2, c3 = n3;
        int tn = t + nw;
        if (tn < NTILES) {
            const float* src = embeds + (size_t)(tn * 16 + m) * DIMS + g * 8;
            n0 = *(const f32x4*)src;       n1 = *(const f32x4*)(src + 4);
            n2 = *(const f32x4*)(src + 32); n3 = *(const f32x4*)(src + 36);
        }
        bf16x8 a0, a1;
        float en = 0.f;
        #pragma unroll
        for (int j = 0; j < 4; ++j) {
            float f0 = c0[j], f1 = c1[j], f2 = c2[j], f3 = c3[j];
            en += f0 * f0 + f1 * f1 + f2 * f2 + f3 * f3;
            a0[j] = f2bf(f0); a0[j + 4] = f2bf(f1);
            a1[j] = f2bf(f2); a1[j + 4] = f2bf(f3);
        }
        en += __shfl_xor(en, 16);
        en += __shfl_xor(en, 32);
        float er[4];
        #pragma unroll
        for (int r = 0; r < 4; ++r) er[r] = __shfl(en, g * 4 + r);

        f32x4 acc[8];
        #pragma unroll
        for (int cb = 0; cb < 8; ++cb) {
            bf16x8 b0 = blds[cb][0][lane];
            bf16x8 b1 = blds[cb][1][lane];
            f32x4 a = {0.f, 0.f, 0.f, 0.f};
            a = __builtin_amdgcn_mfma_f32_16x16x32_bf16(a0, b0, a, 0, 0, 0);
            a = __builtin_amdgcn_mfma_f32_16x16x32_bf16(a1, b1, a, 0, 0, 0);
            acc[cb] = a;
        }

        float rs[4] = {0.f, 0.f, 0.f, 0.f};
        #pragma unroll
        for (int cb = 0; cb < 8; ++cb) {
            #pragma unroll
            for (int r = 0; r < 4; ++r) {
                float sq = fmaxf(er[r] + cnorm[cb] - 2.0f * acc[cb][r], 0.f);
                float dist = frcp(1.0f + sq);
                acc[cb][r] = dist;
                rs[r] += dist;
            }
        }
        #pragma unroll
        for (int r = 0; r < 4; ++r) {
            rs[r] += __shfl_xor(rs[r], 1);
            rs[r] += __shfl_xor(rs[r], 2);
            rs[r] += __shfl_xor(rs[r], 4);
            rs[r] += __shfl_xor(rs[r], 8);
            rs[r] = frcp(rs[r]);
        }
        #pragma unroll
        for (int cb = 0; cb < 8; ++cb) {
            #pragma unroll
            for (int r = 0; r < 4; ++r) csum[cb] += acc[cb][r] * rs[r];
        }
    }

    #pragma unroll
    for (int cb = 0; cb < 8; ++cb) {
        csum[cb] += __shfl_xor(csum[cb], 16);
        csum[cb] += __shfl_xor(csum[cb], 32);
    }
    if (lane < 16) {
        #pragma unroll
        for (int cb = 0; cb < 8; ++cb) cl[wid * 128 + cb * 16 + lane] = csum[cb];
    }
    __syncthreads();
    if (tid < 128) {
        float s = cl[tid] + cl[128 + tid] + cl[256 + tid] + cl[384 + tid];
        colsum_part[(size_t)tid * nblocks + blockIdx.x] = s;   // transposed
    }
}

// K1b: 128 blocks, block k reduces contiguous row k -> invS[k], log2S[k]
__global__ __launch_bounds__(256) void k1b_reduce(
        const float* __restrict__ part, float* __restrict__ invS,
        float* __restrict__ lS, int nb)
{
    __shared__ float lds[4];
    const int k = blockIdx.x;
    const int tid = threadIdx.x, wid = tid >> 6, lane = tid & 63;
    float s = 0.f;
    for (int b = tid; b < nb; b += 256) s += part[(size_t)k * nb + b];
    s += __shfl_xor(s, 1);  s += __shfl_xor(s, 2);  s += __shfl_xor(s, 4);
    s += __shfl_xor(s, 8);  s += __shfl_xor(s, 16); s += __shfl_xor(s, 32);
    if (lane == 0) lds[wid] = s;
    __syncthreads();
    if (tid == 0) {
        float tot = lds[0] + lds[1] + lds[2] + lds[3];
        invS[k] = 1.0f / tot;
        lS[k] = __log2f(tot);
    }
}

// K2: recompute dist, write q, fused loss (log2 domain).
// ILP-2: two independent tile streams per wave to hide shuffle/rcp/log latency.
// NO min-waves bound (R6 lesson: forcing occupancy causes spill catastrophe).
__global__ __launch_bounds__(256) void k2_q_loss(
        const float* __restrict__ embeds, const float* __restrict__ centers,
        const float* __restrict__ invS, const float* __restrict__ lS,
        float* __restrict__ q, float* __restrict__ losspart, int nblocks)
{
    __shared__ bf16x8 blds[8][2][64];
    __shared__ float lds4[4];
    const int tid = threadIdx.x, wid = tid >> 6, lane = tid & 63;
    const int m = lane & 15, g = lane >> 4;

    float cnorm[8];
    stage_centers(centers, blds, cnorm, wid, lane, m, g);

    float invSr[8], lSr[8];
    #pragma unroll
    for (int cb = 0; cb < 8; ++cb) {
        invSr[cb] = invS[cb * 16 + m];
        lSr[cb]   = lS[cb * 16 + m];
    }

    float loss = 0.f;
    const int gwid = blockIdx.x * 4 + wid;
    const int nw = nblocks * 4;

    int t = gwid;
    // ---- pair loop: two independent tiles (t, t+nw) per iteration
    for (; t + nw < NTILES; t += 2 * nw) {
        bf16x8 a0[2], a1[2];
        float er[2][4];
        #pragma unroll
        for (int s = 0; s < 2; ++s) {
            const int tt = t + s * nw;
            const float* src = embeds + (size_t)(tt * 16 + m) * DIMS + g * 8;
            f32x4 c0 = *(const f32x4*)src;       f32x4 c1 = *(const f32x4*)(src + 4);
            f32x4 c2 = *(const f32x4*)(src + 32); f32x4 c3 = *(const f32x4*)(src + 36);
            float en = 0.f;
            #pragma unroll
            for (int j = 0; j < 4; ++j) {
                float f0 = c0[j], f1 = c1[j], f2 = c2[j], f3 = c3[j];
                en += f0 * f0 + f1 * f1 + f2 * f2 + f3 * f3;
                a0[s][j] = f2bf(f0); a0[s][j + 4] = f2bf(f1);
                a1[s][j] = f2bf(f2); a1[s][j + 4] = f2bf(f3);
            }
            en += __shfl_xor(en, 16);
            en += __shfl_xor(en, 32);
            #pragma unroll
            for (int r = 0; r < 4; ++r) er[s][r] = __shfl(en, g * 4 + r);
        }

        f32x4 acc[2][8];
        #pragma unroll
        for (int s = 0; s < 2; ++s) {
            #pragma unroll
            for (int cb = 0; cb < 8; ++cb) {
                bf16x8 b0 = blds[cb][0][lane];
                bf16x8 b1 = blds[cb][1][lane];
                f32x4 a = {0.f, 0.f, 0.f, 0.f};
                a = __builtin_amdgcn_mfma_f32_16x16x32_bf16(a0[s], b0, a, 0, 0, 0);
                a = __builtin_amdgcn_mfma_f32_16x16x32_bf16(a1[s], b1, a, 0, 0, 0);
                acc[s][cb] = a;
            }
        }

        float rs[2][4] = {{0.f,0.f,0.f,0.f},{0.f,0.f,0.f,0.f}};
        #pragma unroll
        for (int s = 0; s < 2; ++s)
            #pragma unroll
            for (int cb = 0; cb < 8; ++cb)
                #pragma unroll
                for (int r = 0; r < 4; ++r) {
                    float sq = fmaxf(er[s][r] + cnorm[cb] - 2.0f * acc[s][cb][r], 0.f);
                    float dist = frcp(1.0f + sq);
                    acc[s][cb][r] = dist;
                    rs[s][r] += dist;
                }
        #pragma unroll
        for (int s = 0; s < 2; ++s)
            #pragma unroll
            for (int r = 0; r < 4; ++r) {
                rs[s][r] += __shfl_xor(rs[s][r], 1);
                rs[s][r] += __shfl_xor(rs[s][r], 2);
                rs[s][r] += __shfl_xor(rs[s][r], 4);
                rs[s][r] += __shfl_xor(rs[s][r], 8);
                rs[s][r] = frcp(rs[s][r]);
            }

        float W[2][4] = {{0.f,0.f,0.f,0.f},{0.f,0.f,0.f,0.f}};
        #pragma unroll
        for (int s = 0; s < 2; ++s) {
            const int tt = t + s * nw;
            #pragma unroll
            for (int cb = 0; cb < 8; ++cb)
                #pragma unroll
                for (int r = 0; r < 4; ++r) {
                    float qv = acc[s][cb][r] * rs[s][r];
                    acc[s][cb][r] = qv;
                    q[(size_t)(tt * 16 + g * 4 + r) * KC + cb * 16 + m] = qv;
                    W[s][r] += qv * qv * invSr[cb];
                }
        }
        float iw[2][4], lw[2][4];
        #pragma unroll
        for (int s = 0; s < 2; ++s)
            #pragma unroll
            for (int r = 0; r < 4; ++r) {
                W[s][r] += __shfl_xor(W[s][r], 1);
                W[s][r] += __shfl_xor(W[s][r], 2);
                W[s][r] += __shfl_xor(W[s][r], 4);
                W[s][r] += __shfl_xor(W[s][r], 8);
                iw[s][r] = frcp(W[s][r]);
                lw[s][r] = __log2f(W[s][r]);
            }
        #pragma unroll
        for (int s = 0; s < 2; ++s)
            #pragma unroll
            for (int cb = 0; cb < 8; ++cb)
                #pragma unroll
                for (int r = 0; r < 4; ++r) {
                    float qv = acc[s][cb][r];
                    float w = qv * qv * invSr[cb];
                    loss += w * iw[s][r] * (__log2f(qv) - lSr[cb] - lw[s][r]);
                }
    }

    // ---- single-tile tail
    if (t < NTILES) {
        const float* src = embeds + (size_t)(t * 16 + m) * DIMS + g * 8;
        f32x4 c0 = *(const f32x4*)src;       f32x4 c1 = *(const f32x4*)(src + 4);
        f32x4 c2 = *(const f32x4*)(src + 32); f32x4 c3 = *(const f32x4*)(src + 36);
        bf16x8 a0, a1;
        float en = 0.f;
        #pragma unroll
        for (int j = 0; j < 4; ++j) {
            float f0 = c0[j], f1 = c1[j], f2 = c2[j], f3 = c3[j];
            en += f0 * f0 + f1 * f1 + f2 * f2 + f3 * f3;
            a0[j] = f2bf(f0); a0[j + 4] = f2bf(f1);
            a1[j] = f2bf(f2); a1[j + 4] = f2bf(f3);
        }
        en += __shfl_xor(en, 16);
        en += __shfl_xor(en, 32);
        float er[4];
        #pragma unroll
        for (int r = 0; r < 4; ++r) er[r] = __shfl(en, g * 4 + r);

        f32x4 acc[8];
        #pragma unroll
        for (int cb = 0; cb < 8; ++cb) {
            bf16x8 b0 = blds[cb][0][lane];
            bf16x8 b1 = blds[cb][1][lane];
            f32x4 a = {0.f, 0.f, 0.f, 0.f};
            a = __builtin_amdgcn_mfma_f32_16x16x32_bf16(a0, b0, a, 0, 0, 0);
            a = __builtin_amdgcn_mfma_f32_16x16x32_bf16(a1, b1, a, 0, 0, 0);
            acc[cb] = a;
        }

        float rs[4] = {0.f, 0.f, 0.f, 0.f};
        #pragma unroll
        for (int cb = 0; cb < 8; ++cb)
            #pragma unroll
            for (int r = 0; r < 4; ++r) {
                float sq = fmaxf(er[r] + cnorm[cb] - 2.0f * acc[cb][r], 0.f);
                float dist = frcp(1.0f + sq);
                acc[cb][r] = dist;
                rs[r] += dist;
            }
        #pragma unroll
        for (int r = 0; r < 4; ++r) {
            rs[r] += __shfl_xor(rs[r], 1);
            rs[r] += __shfl_xor(rs[r], 2);
            rs[r] += __shfl_xor(rs[r], 4);
            rs[r] += __shfl_xor(rs[r], 8);
            rs[r] = frcp(rs[r]);
        }

        float W[4] = {0.f, 0.f, 0.f, 0.f};
        #pragma unroll
        for (int cb = 0; cb < 8; ++cb)
            #pragma unroll
            for (int r = 0; r < 4; ++r) {
                float qv = acc[cb][r] * rs[r];
                acc[cb][r] = qv;
                q[(size_t)(t * 16 + g * 4 + r) * KC + cb * 16 + m] = qv;
                W[r] += qv * qv * invSr[cb];
            }
        float iw[4], lw[4];
        #pragma unroll
        for (int r = 0; r < 4; ++r) {
            W[r] += __shfl_xor(W[r], 1);
            W[r] += __shfl_xor(W[r], 2);
            W[r] += __shfl_xor(W[r], 4);
            W[r] += __shfl_xor(W[r], 8);
            iw[r] = frcp(W[r]);
            lw[r] = __log2f(W[r]);
        }
        #pragma unroll
        for (int cb = 0; cb < 8; ++cb)
            #pragma unroll
            for (int r = 0; r < 4; ++r) {
                float qv = acc[cb][r];
                float w = qv * qv * invSr[cb];
                loss += w * iw[r] * (__log2f(qv) - lSr[cb] - lw[r]);
            }
    }

    loss += __shfl_xor(loss, 1);  loss += __shfl_xor(loss, 2);
    loss += __shfl_xor(loss, 4);  loss += __shfl_xor(loss, 8);
    loss += __shfl_xor(loss, 16); loss += __shfl_xor(loss, 32);
    if (lane == 0) lds4[wid] = loss;
    __syncthreads();
    if (tid == 0) losspart[blockIdx.x] = lds4[0] + lds4[1] + lds4[2] + lds4[3];
}

// K2b: final loss reduce; convert log2 -> ln
__global__ __launch_bounds__(1024) void k2b_final(
        const float* __restrict__ losspart, int nb, float* __restrict__ out)
{
    __shared__ float lds[16];
    const int tid = threadIdx.x;
    float s = 0.f;
    for (int b = tid; b < nb; b += 1024) s += losspart[b];
    s += __shfl_xor(s, 1);  s += __shfl_xor(s, 2);  s += __shfl_xor(s, 4);
    s += __shfl_xor(s, 8);  s += __shfl_xor(s, 16); s += __shfl_xor(s, 32);
    if ((tid & 63) == 0) lds[tid >> 6] = s;
    __syncthreads();
    if (tid == 0) {
        float tot = 0.f;
        #pragma unroll
        for (int i = 0; i < 16; ++i) tot += lds[i];
        out[0] = (float)((double)tot * 0.6931471805599453 /
                         (double)((size_t)NROWS * KC));
    }
}

extern "C" void kernel_launch(void* const* d_in, const int* in_sizes, int n_in,
                              void* d_out, int out_size, void* d_ws, size_t ws_size,
                              hipStream_t stream)
{
    const float* embeds  = (const float*)d_in[0];
    const float* centers = (const float*)d_in[1];
    float* out  = (float*)d_out;
    float* qbuf = out + 1;
    float* ws   = (float*)d_ws;

    const int GB1 = 512, GB2 = 512;
    float* colsum_part = ws;                          // 128 * GB1 (transposed)
    float* invS  = ws + (size_t)GB1 * 128;            // 128
    float* lS    = invS + 128;                        // 128
    float* lpart = lS + 128;                          // GB2

    hipLaunchKernelGGL(k1_colsum, dim3(GB1), dim3(256), 0, stream,
                       embeds, centers, colsum_part, GB1);
    hipLaunchKernelGGL(k1b_reduce, dim3(128), dim3(256), 0, stream,
                       colsum_part, invS, lS, GB1);
    hipLaunchKernelGGL(k2_q_loss, dim3(GB2), dim3(256), 0, stream,
                       embeds, centers, invS, lS, qbuf, lpart, GB2);
    hipLaunchKernelGGL(k2b_final, dim3(1), dim3(1024), 0, stream,
                       lpart, GB2, out);
}

// Round 8
// 97.673 us; speedup vs baseline: 4.8254x; 1.2410x over previous
//
#include <hip/hip_runtime.h>
#include <stdint.h>
#include <stddef.h>

typedef __attribute__((ext_vector_type(8))) short bf16x8;
typedef __attribute__((ext_vector_type(4))) float f32x4;

#define NROWS 400000
#define KC 128
#define DIMS 64
#define NTILES (NROWS / 16)

__device__ __forceinline__ short f2bf(float f) {
    union { float f; uint32_t u; } v; v.f = f;
    uint32_t u = v.u;
    uint32_t r = (u + 0x7FFFu + ((u >> 16) & 1u)) >> 16;  // RNE, finite inputs
    return (short)r;
}

__device__ __forceinline__ float frcp(float x) { return __builtin_amdgcn_rcpf(x); }

// Stage -2*centers bf16 fragments (A-operand) into LDS + center norms into cnLDS.
// A-operand layout for mfma(A,B,C): lane (m,g) holds A[m][8g+i] -> center cb*16+m.
__device__ __forceinline__ void stage_centers_T(
        const float* __restrict__ centers, bf16x8 (*blds)[2][64],
        float* cnLDS, int wid, int lane, int m, int g)
{
    #pragma unroll
    for (int cb = 0; cb < 8; ++cb) {
        float cacc = 0.f;
        bf16x8 bfr[2];
        #pragma unroll
        for (int h = 0; h < 2; ++h) {
            const float* src = centers + (size_t)(cb * 16 + m) * DIMS + h * 32 + g * 8;
            f32x4 c0 = *(const f32x4*)src;
            f32x4 c1 = *(const f32x4*)(src + 4);
            bf16x8 b;
            #pragma unroll
            for (int j = 0; j < 4; ++j) {
                float f0 = c0[j], f1 = c1[j];
                cacc += f0 * f0 + f1 * f1;
                b[j]     = f2bf(-2.0f * f0);   // exact scale; folds -2*dot into MFMA
                b[j + 4] = f2bf(-2.0f * f1);
            }
            bfr[h] = b;
        }
        cacc += __shfl_xor(cacc, 16);
        cacc += __shfl_xor(cacc, 32);
        if (wid == 0) {
            blds[cb][0][lane] = bfr[0];
            blds[cb][1][lane] = bfr[1];
            if (g == 0) cnLDS[cb * 16 + m] = cacc;   // lanes 0..15 cover all 16 rows
        }
    }
    __syncthreads();
}

// K1: column sums of q. Transposed-output MFMA: D[k_local=4g+r][n=m].
__global__ __launch_bounds__(256) void k1_colsum(
        const float* __restrict__ embeds, const float* __restrict__ centers,
        float* __restrict__ colsum_part, int nblocks)
{
    __shared__ bf16x8 blds[8][2][64];
    __shared__ float cnLDS[128];
    __shared__ float cl[4 * 128];
    const int tid = threadIdx.x, wid = tid >> 6, lane = tid & 63;
    const int m = lane & 15, g = lane >> 4;

    stage_centers_T(centers, blds, cnLDS, wid, lane, m, g);

    f32x4 cnr[8];
    #pragma unroll
    for (int cb = 0; cb < 8; ++cb) cnr[cb] = *(const f32x4*)&cnLDS[cb * 16 + g * 4];

    float csum[8][4];
    #pragma unroll
    for (int cb = 0; cb < 8; ++cb)
        #pragma unroll
        for (int r = 0; r < 4; ++r) csum[cb][r] = 0.f;

    const int gwid = blockIdx.x * 4 + wid;
    const int nw = nblocks * 4;

    int t = gwid;
    f32x4 n0, n1, n2, n3;
    if (t < NTILES) {
        const float* src = embeds + (size_t)(t * 16 + m) * DIMS + g * 8;
        n0 = *(const f32x4*)src;       n1 = *(const f32x4*)(src + 4);
        n2 = *(const f32x4*)(src + 32); n3 = *(const f32x4*)(src + 36);
    }
    for (; t < NTILES; t += nw) {
        f32x4 c0 = n0, c1 = n1, c2 = n2, c3 = n3;
        int tn = t + nw;
        if (tn < NTILES) {
            const float* src = embeds + (size_t)(tn * 16 + m) * DIMS + g * 8;
            n0 = *(const f32x4*)src;       n1 = *(const f32x4*)(src + 4);
            n2 = *(const f32x4*)(src + 32); n3 = *(const f32x4*)(src + 36);
        }
        bf16x8 a0, a1;
        float en = 0.f;
        #pragma unroll
        for (int j = 0; j < 4; ++j) {
            float f0 = c0[j], f1 = c1[j], f2 = c2[j], f3 = c3[j];
            en += f0 * f0 + f1 * f1 + f2 * f2 + f3 * f3;
            a0[j] = f2bf(f0); a0[j + 4] = f2bf(f1);
            a1[j] = f2bf(f2); a1[j + 4] = f2bf(f3);
        }
        en += __shfl_xor(en, 16);
        en += __shfl_xor(en, 32);     // norm of embed row m, at every lane

        f32x4 acc[8];
        #pragma unroll
        for (int cb = 0; cb < 8; ++cb) {
            f32x4 a;
            #pragma unroll
            for (int r = 0; r < 4; ++r) a[r] = cnr[cb][r] + en;   // C = |c|^2 + |e|^2
            a = __builtin_amdgcn_mfma_f32_16x16x32_bf16(blds[cb][0][lane], a0, a, 0, 0, 0);
            a = __builtin_amdgcn_mfma_f32_16x16x32_bf16(blds[cb][1][lane], a1, a, 0, 0, 0);
            acc[cb] = a;              // = sq[k][n]
        }

        float rsp = 0.f;
        #pragma unroll
        for (int cb = 0; cb < 8; ++cb)
            #pragma unroll
            for (int r = 0; r < 4; ++r) {
                float dist = frcp(1.0f + fmaxf(acc[cb][r], 0.f));
                acc[cb][r] = dist;
                rsp += dist;
            }
        rsp += __shfl_xor(rsp, 16);
        rsp += __shfl_xor(rsp, 32);   // row-sum over all 128 k for row m
        float invR = frcp(rsp);

        #pragma unroll
        for (int cb = 0; cb < 8; ++cb)
            #pragma unroll
            for (int r = 0; r < 4; ++r) csum[cb][r] += acc[cb][r] * invR;
    }

    // butterfly over m-lanes (bits 0..3): colsum for k = cb*16 + 4g + r
    #pragma unroll
    for (int cb = 0; cb < 8; ++cb)
        #pragma unroll
        for (int r = 0; r < 4; ++r) {
            float v = csum[cb][r];
            v += __shfl_xor(v, 1); v += __shfl_xor(v, 2);
            v += __shfl_xor(v, 4); v += __shfl_xor(v, 8);
            csum[cb][r] = v;
        }
    if (m == 0) {
        #pragma unroll
        for (int cb = 0; cb < 8; ++cb) {
            f32x4 v = {csum[cb][0], csum[cb][1], csum[cb][2], csum[cb][3]};
            *(f32x4*)&cl[wid * 128 + cb * 16 + g * 4] = v;
        }
    }
    __syncthreads();
    if (tid < 128) {
        float s = cl[tid] + cl[128 + tid] + cl[256 + tid] + cl[384 + tid];
        colsum_part[(size_t)tid * nblocks + blockIdx.x] = s;   // transposed
    }
}

// K1b: 128 blocks, block k reduces contiguous row k -> invS[k], log2S[k]
__global__ __launch_bounds__(256) void k1b_reduce(
        const float* __restrict__ part, float* __restrict__ invS,
        float* __restrict__ lS, int nb)
{
    __shared__ float lds[4];
    const int k = blockIdx.x;
    const int tid = threadIdx.x, wid = tid >> 6, lane = tid & 63;
    float s = 0.f;
    for (int b = tid; b < nb; b += 256) s += part[(size_t)k * nb + b];
    s += __shfl_xor(s, 1);  s += __shfl_xor(s, 2);  s += __shfl_xor(s, 4);
    s += __shfl_xor(s, 8);  s += __shfl_xor(s, 16); s += __shfl_xor(s, 32);
    if (lane == 0) lds[wid] = s;
    __syncthreads();
    if (tid == 0) {
        float tot = lds[0] + lds[1] + lds[2] + lds[3];
        invS[k] = 1.0f / tot;
        lS[k] = __log2f(tot);
    }
}

// K2: recompute sq via transposed MFMA, write q, fused loss (log2 domain).
__global__ __launch_bounds__(256) void k2_q_loss(
        const float* __restrict__ embeds, const float* __restrict__ centers,
        const float* __restrict__ invS, const float* __restrict__ lS,
        float* __restrict__ q, float* __restrict__ losspart, int nblocks)
{
    __shared__ bf16x8 blds[8][2][64];
    __shared__ float cnLDS[128], isLDS[128], lsLDS[128];
    __shared__ float lds4[4];
    const int tid = threadIdx.x, wid = tid >> 6, lane = tid & 63;
    const int m = lane & 15, g = lane >> 4;

    if (tid < 128) { isLDS[tid] = invS[tid]; lsLDS[tid] = lS[tid]; }
    stage_centers_T(centers, blds, cnLDS, wid, lane, m, g);  // has __syncthreads

    f32x4 cnr[8], isr[8], lsr[8];
    #pragma unroll
    for (int cb = 0; cb < 8; ++cb) {
        cnr[cb] = *(const f32x4*)&cnLDS[cb * 16 + g * 4];
        isr[cb] = *(const f32x4*)&isLDS[cb * 16 + g * 4];
        lsr[cb] = *(const f32x4*)&lsLDS[cb * 16 + g * 4];
    }

    float loss = 0.f;
    const int gwid = blockIdx.x * 4 + wid;
    const int nw = nblocks * 4;

    int t = gwid;
    f32x4 n0, n1, n2, n3;
    if (t < NTILES) {
        const float* src = embeds + (size_t)(t * 16 + m) * DIMS + g * 8;
        n0 = *(const f32x4*)src;       n1 = *(const f32x4*)(src + 4);
        n2 = *(const f32x4*)(src + 32); n3 = *(const f32x4*)(src + 36);
    }
    for (; t < NTILES; t += nw) {
        f32x4 c0 = n0, c1 = n1, c2 = n2, c3 = n3;
        int tn = t + nw;
        if (tn < NTILES) {
            const float* src = embeds + (size_t)(tn * 16 + m) * DIMS + g * 8;
            n0 = *(const f32x4*)src;       n1 = *(const f32x4*)(src + 4);
            n2 = *(const f32x4*)(src + 32); n3 = *(const f32x4*)(src + 36);
        }
        bf16x8 a0, a1;
        float en = 0.f;
        #pragma unroll
        for (int j = 0; j < 4; ++j) {
            float f0 = c0[j], f1 = c1[j], f2 = c2[j], f3 = c3[j];
            en += f0 * f0 + f1 * f1 + f2 * f2 + f3 * f3;
            a0[j] = f2bf(f0); a0[j + 4] = f2bf(f1);
            a1[j] = f2bf(f2); a1[j + 4] = f2bf(f3);
        }
        en += __shfl_xor(en, 16);
        en += __shfl_xor(en, 32);

        f32x4 acc[8];
        #pragma unroll
        for (int cb = 0; cb < 8; ++cb) {
            f32x4 a;
            #pragma unroll
            for (int r = 0; r < 4; ++r) a[r] = cnr[cb][r] + en;
            a = __builtin_amdgcn_mfma_f32_16x16x32_bf16(blds[cb][0][lane], a0, a, 0, 0, 0);
            a = __builtin_amdgcn_mfma_f32_16x16x32_bf16(blds[cb][1][lane], a1, a, 0, 0, 0);
            acc[cb] = a;
        }

        float rsp = 0.f;
        #pragma unroll
        for (int cb = 0; cb < 8; ++cb)
            #pragma unroll
            for (int r = 0; r < 4; ++r) {
                float dist = frcp(1.0f + fmaxf(acc[cb][r], 0.f));
                acc[cb][r] = dist;
                rsp += dist;
            }
        rsp += __shfl_xor(rsp, 16);
        rsp += __shfl_xor(rsp, 32);
        float invR = frcp(rsp);

        // q = dist*invR: store (scalar dword; d_out+1 is only 4B-aligned) + W partial
        float Wp = 0.f;
        float* qrow = q + (size_t)(t * 16 + m) * KC + g * 4;
        #pragma unroll
        for (int cb = 0; cb < 8; ++cb)
            #pragma unroll
            for (int r = 0; r < 4; ++r) {
                float qv = acc[cb][r] * invR;
                acc[cb][r] = qv;
                qrow[cb * 16 + r] = qv;
                Wp += qv * qv * isr[cb][r];
            }
        Wp += __shfl_xor(Wp, 16);
        Wp += __shfl_xor(Wp, 32);
        float iw = frcp(Wp);
        float lw = __log2f(Wp);

        #pragma unroll
        for (int cb = 0; cb < 8; ++cb)
            #pragma unroll
            for (int r = 0; r < 4; ++r) {
                float qv = acc[cb][r];
                float w = qv * qv * isr[cb][r];
                loss += w * iw * (__log2f(qv) - lsr[cb][r] - lw);
            }
    }

    loss += __shfl_xor(loss, 1);  loss += __shfl_xor(loss, 2);
    loss += __shfl_xor(loss, 4);  loss += __shfl_xor(loss, 8);
    loss += __shfl_xor(loss, 16); loss += __shfl_xor(loss, 32);
    if (lane == 0) lds4[wid] = loss;
    __syncthreads();
    if (tid == 0) losspart[blockIdx.x] = lds4[0] + lds4[1] + lds4[2] + lds4[3];
}

// K2b: final loss reduce; convert log2 -> ln
__global__ __launch_bounds__(1024) void k2b_final(
        const float* __restrict__ losspart, int nb, float* __restrict__ out)
{
    __shared__ float lds[16];
    const int tid = threadIdx.x;
    float s = 0.f;
    for (int b = tid; b < nb; b += 1024) s += losspart[b];
    s += __shfl_xor(s, 1);  s += __shfl_xor(s, 2);  s += __shfl_xor(s, 4);
    s += __shfl_xor(s, 8);  s += __shfl_xor(s, 16); s += __shfl_xor(s, 32);
    if ((tid & 63) == 0) lds[tid >> 6] = s;
    __syncthreads();
    if (tid == 0) {
        float tot = 0.f;
        #pragma unroll
        for (int i = 0; i < 16; ++i) tot += lds[i];
        out[0] = (float)((double)tot * 0.6931471805599453 /
                         (double)((size_t)NROWS * KC));
    }
}

extern "C" void kernel_launch(void* const* d_in, const int* in_sizes, int n_in,
                              void* d_out, int out_size, void* d_ws, size_t ws_size,
                              hipStream_t stream)
{
    const float* embeds  = (const float*)d_in[0];
    const float* centers = (const float*)d_in[1];
    float* out  = (float*)d_out;
    float* qbuf = out + 1;
    float* ws   = (float*)d_ws;

    const int GB1 = 512, GB2 = 512;
    float* colsum_part = ws;                          // 128 * GB1 (transposed)
    float* invS  = ws + (size_t)GB1 * 128;            // 128
    float* lS    = invS + 128;                        // 128
    float* lpart = lS + 128;                          // GB2

    hipLaunchKernelGGL(k1_colsum, dim3(GB1), dim3(256), 0, stream,
                       embeds, centers, colsum_part, GB1);
    hipLaunchKernelGGL(k1b_reduce, dim3(128), dim3(256), 0, stream,
                       colsum_part, invS, lS, GB1);
    hipLaunchKernelGGL(k2_q_loss, dim3(GB2), dim3(256), 0, stream,
                       embeds, centers, invS, lS, qbuf, lpart, GB2);
    hipLaunchKernelGGL(k2b_final, dim3(1), dim3(1024), 0, stream,
                       lpart, GB2, out);
}